// Round 3
// baseline (612.352 us; speedup 1.0000x reference)
//
#include <hip/hip_runtime.h>

// Patient2Vec forward, MI355X/gfx950.
// Sizes: B=128,S=64,P=32,D=256,E=256,H=128,3H=384,L=2,A=1,O=2.
// Inputs fp32, outputs fp32 (reference is pure float32; round-2 forensics:
// out-chunk absmax 1.49 > 1 is only possible if harness reads d_out as fp32).
// alpha = softmax over size-1 axis == 1.0 exactly; context = sum_t states.

using u16 = unsigned short;
using u32 = unsigned int;

typedef __bf16 bf16x8 __attribute__((ext_vector_type(8)));
typedef float  f32x4  __attribute__((ext_vector_type(4)));

__device__ __forceinline__ float bf2f(u16 u) {
  union { u32 i; float f; } v; v.i = ((u32)u) << 16; return v.f;
}
__device__ __forceinline__ u16 f2bf(float f) {
  union { float f; u32 i; } v; v.f = f;
  u32 i = v.i;
  u32 r = (i + 0x7FFFu + ((i >> 16) & 1u)) >> 16;
  return (u16)r;
}
__device__ __forceinline__ float sigm(float x) { return 1.f / (1.f + __expf(-x)); }
__device__ __forceinline__ float tanh_f(float x) { return 1.f - 2.f / (1.f + __expf(2.f * x)); }

// ---------------------------------------------------------------------------
// K0: weight conversion. embed_w fp32 -> hi/lo bf16; Wih fp32 -> bf16.
// grid covers 393216 threads (Wih count); first 65536 also do embed_w.
// ---------------------------------------------------------------------------
__global__ __launch_bounds__(256) void k_cvt(
    const float* __restrict__ embw, const float* __restrict__ Wih,
    u16* __restrict__ embHi, u16* __restrict__ embLo, u16* __restrict__ wihB) {
  const int i = blockIdx.x * 256 + threadIdx.x;
  if (i < 65536) {
    float v = embw[i];
    u16 h = f2bf(v);
    embHi[i] = h;
    embLo[i] = f2bf(v - bf2f(h));
  }
  wihB[i] = f2bf(Wih[i]);
}

// ---------------------------------------------------------------------------
// K1: conv — per (b,s): s_p = dot(inputs[b,s,p,:], conv_w)+cb;
//           conv_all[k] = sum_p s_p * inputs[b,s,p,k]
// fp32 in; emits hi/lo bf16 split of fp32 conv_all (for embed MFMA precision).
// ---------------------------------------------------------------------------
__global__ __launch_bounds__(256) void k_conv(
    const float* __restrict__ inp, const float* __restrict__ cw,
    const float* __restrict__ cb, u16* __restrict__ chi, u16* __restrict__ clo) {
  __shared__ float tile[32 * 256];  // 32 KiB
  __shared__ float cwf[256];
  __shared__ float s_p[32];
  const int bs  = blockIdx.x;
  const int tid = threadIdx.x;
  const float* src = inp + (size_t)bs * 8192;
#pragma unroll
  for (int i = 0; i < 8; i++) {
    int idx = i * 1024 + tid * 4;
    *(float4*)&tile[idx] = *(const float4*)&src[idx];
  }
  cwf[tid] = cw[tid];
  __syncthreads();
  const int wv = tid >> 6, ln = tid & 63;
  const float cbf = cb[0];
  for (int pp = 0; pp < 8; pp++) {
    int p = wv * 8 + pp;
    float part = 0.f;
#pragma unroll
    for (int q = 0; q < 4; q++) {
      int k = ln + q * 64;
      part += tile[p * 256 + k] * cwf[k];
    }
    for (int off = 32; off; off >>= 1) part += __shfl_xor(part, off, 64);
    if (ln == 0) s_p[p] = part + cbf;
  }
  __syncthreads();
  float acc = 0.f;
  const int k = tid;
#pragma unroll
  for (int p = 0; p < 32; p++) acc += s_p[p] * tile[p * 256 + k];
  u16 hi = f2bf(acc);
  float lo = acc - bf2f(hi);
  chi[(size_t)bs * 256 + k] = hi;
  clo[(size_t)bs * 256 + k] = f2bf(lo);
}

// ---------------------------------------------------------------------------
// K2: MFMA GEMM  C[m,n] = act( A[m,:]·W[n,:] (+Alo·W) (+A·Wlo) + bias[n] )
// A:[M,K] bf16 row-major, W:[N,K] bf16 row-major (B^T pattern, m92-verified).
// 64x64 tile, 256 thr (4 waves), wave w -> rows w*16..+15 x 64 cols.
// mfma_f32_16x16x32_bf16: A-frag A[m=l&15][k=(l>>4)*8+j]; B-frag = W rows same
// pattern; C/D row=(l>>4)*4+r, col=l&15.  LDS rows stride 56 (16B-aligned).
// ---------------------------------------------------------------------------
template <bool HAS_ALO, bool HAS_WLO, bool HAS_BIAS, bool CLIP, bool OUT_BF16>
__global__ __launch_bounds__(256) void k_gemm(
    const u16* __restrict__ A, const u16* __restrict__ Alo,
    const u16* __restrict__ W, const u16* __restrict__ Wlo,
    const float* __restrict__ bias,
    void* __restrict__ Cout, int M, int N, int K) {
  const int LDT = 56;
  __shared__ u16 As[64 * 56];
  __shared__ u16 La[64 * 56];
  __shared__ u16 Ws[64 * 56];
  __shared__ u16 Lw[64 * 56];
  const int tid = threadIdx.x;
  const int m0 = blockIdx.x * 64, n0 = blockIdx.y * 64;
  const int wv = tid >> 6, ln = tid & 63;
  const int lm = ln & 15, lk = (ln >> 4) * 8;
  const int srow = tid >> 2, sgrp = tid & 3;

  f32x4 acc[4];
#pragma unroll
  for (int nt = 0; nt < 4; nt++) acc[nt] = (f32x4){0.f, 0.f, 0.f, 0.f};

  for (int kc = 0; kc < K; kc += 32) {
    __syncthreads();
    *(uint4*)&As[srow * LDT + sgrp * 8] =
        *(const uint4*)&A[(size_t)(m0 + srow) * K + kc + sgrp * 8];
    *(uint4*)&Ws[srow * LDT + sgrp * 8] =
        *(const uint4*)&W[(size_t)(n0 + srow) * K + kc + sgrp * 8];
    if (HAS_ALO)
      *(uint4*)&La[srow * LDT + sgrp * 8] =
          *(const uint4*)&Alo[(size_t)(m0 + srow) * K + kc + sgrp * 8];
    if (HAS_WLO)
      *(uint4*)&Lw[srow * LDT + sgrp * 8] =
          *(const uint4*)&Wlo[(size_t)(n0 + srow) * K + kc + sgrp * 8];
    __syncthreads();

    bf16x8 af = *(const bf16x8*)&As[(wv * 16 + lm) * LDT + lk];
    bf16x8 bfr[4];
#pragma unroll
    for (int nt = 0; nt < 4; nt++)
      bfr[nt] = *(const bf16x8*)&Ws[(nt * 16 + lm) * LDT + lk];
#pragma unroll
    for (int nt = 0; nt < 4; nt++)
      acc[nt] = __builtin_amdgcn_mfma_f32_16x16x32_bf16(af, bfr[nt], acc[nt], 0, 0, 0);
    if (HAS_ALO) {
      bf16x8 lf = *(const bf16x8*)&La[(wv * 16 + lm) * LDT + lk];
#pragma unroll
      for (int nt = 0; nt < 4; nt++)
        acc[nt] = __builtin_amdgcn_mfma_f32_16x16x32_bf16(lf, bfr[nt], acc[nt], 0, 0, 0);
    }
    if (HAS_WLO) {
#pragma unroll
      for (int nt = 0; nt < 4; nt++) {
        bf16x8 wl = *(const bf16x8*)&Lw[(nt * 16 + lm) * LDT + lk];
        acc[nt] = __builtin_amdgcn_mfma_f32_16x16x32_bf16(af, wl, acc[nt], 0, 0, 0);
      }
    }
  }

  const int rbase = m0 + wv * 16 + (ln >> 4) * 4;
#pragma unroll
  for (int nt = 0; nt < 4; nt++) {
    const int col = n0 + nt * 16 + lm;
    const float bv = HAS_BIAS ? bias[col] : 0.f;
#pragma unroll
    for (int r = 0; r < 4; r++) {
      float v = acc[nt][r] + bv;
      if (CLIP) v = fminf(fmaxf(v, -1.f), 1.f);
      const int row = rbase + r;
      if (OUT_BF16)
        ((u16*)Cout)[(size_t)row * N + col] = f2bf(v);
      else
        ((float*)Cout)[(size_t)row * N + col] = v;
    }
  }
}

// ---------------------------------------------------------------------------
// K3: GRU layer, one (b,dir) chain per workgroup (256 WGs = 256 CUs).
// 384 threads: thread r holds Whh row r (128 fp32) in registers.
// Per step: gh[r] = dot(w_r, h) + bhh[r] (h broadcast from LDS), barrier,
// threads 0..127 combine gates, update h, write states. Two barriers/step.
// torch cell: r=sig(xr+hr); z=sig(xz+hz); n=tanh(xn+r*hn); h=(1-z)n+z*h.
// st_bf: bf16 states (layer0 -> feeds next GEMM) or null.
// st_f:  fp32 states (layer1 -> d_out) or null; ctx: fp32 context or null.
// ---------------------------------------------------------------------------
__global__ __launch_bounds__(384) void k_gru(
    const float* __restrict__ xg,   // [B*S, 768], this layer (dir0 cols 0..383)
    const float* __restrict__ Whh,  // [2,384,128] layer slice, fp32
    const float* __restrict__ bhh,  // [2,384] layer slice, fp32
    u16* __restrict__ st_bf,        // [B,S,256] bf16 or null
    float* __restrict__ st_f,       // [B,S,256] fp32 or null
    float* __restrict__ ctx) {      // [B,256] fp32 or null
  __shared__ float gh[384];
  __shared__ float hf[128];
  const int dir = blockIdx.x & 1, b = blockIdx.x >> 1;
  const int r = threadIdx.x;

  float w[128];
  const float4* wrow = (const float4*)(Whh + ((size_t)dir * 384 + r) * 128);
#pragma unroll
  for (int i = 0; i < 32; i++) {
    float4 q = wrow[i];
    w[4 * i]     = q.x;
    w[4 * i + 1] = q.y;
    w[4 * i + 2] = q.z;
    w[4 * i + 3] = q.w;
  }
  const float bhv = bhh[dir * 384 + r];
  if (r < 128) hf[r] = 0.f;
  float csum = 0.f;
  __syncthreads();

  for (int ti = 0; ti < 64; ti++) {
    const int t = dir ? (63 - ti) : ti;
    float a = bhv;
    const float4* hv = (const float4*)hf;
#pragma unroll
    for (int kk = 0; kk < 32; kk++) {
      float4 h4 = hv[kk];
      a += w[4 * kk] * h4.x + w[4 * kk + 1] * h4.y +
           w[4 * kk + 2] * h4.z + w[4 * kk + 3] * h4.w;
    }
    gh[r] = a;
    __syncthreads();
    if (r < 128) {
      const float* xrow = xg + (size_t)(b * 64 + t) * 768 + dir * 384;
      float xr = xrow[r], xz = xrow[128 + r], xn = xrow[256 + r];
      float rg = sigm(xr + gh[r]);
      float zg = sigm(xz + gh[128 + r]);
      float ng = tanh_f(xn + rg * gh[256 + r]);
      float hp = hf[r];
      float hn = (1.f - zg) * ng + zg * hp;
      hf[r] = hn;
      const size_t oi = (size_t)(b * 64 + t) * 256 + dir * 128 + r;
      if (st_bf) st_bf[oi] = f2bf(hn);
      if (st_f)  st_f[oi]  = hn;
      csum += hn;
    }
    __syncthreads();
  }
  if (ctx != nullptr && r < 128)
    ctx[(size_t)b * 256 + dir * 128 + r] = csum;
}

// ---------------------------------------------------------------------------
// K4: final — out = softmax(context @ lin_w^T + lin_b) over O=2; alpha = 1.0.
// All fp32 outputs.
// ---------------------------------------------------------------------------
__global__ __launch_bounds__(256) void k_final(
    const float* __restrict__ ctx, const float* __restrict__ lw,
    const float* __restrict__ lb, float* __restrict__ out,
    float* __restrict__ alpha) {
  const int tid = threadIdx.x;
  if (tid < 128) {
    const int b = tid;
    float a0 = lb[0], a1 = lb[1];
    for (int k = 0; k < 256; k++) {
      float c = ctx[b * 256 + k];
      a0 += c * lw[k];
      a1 += c * lw[256 + k];
    }
    float m = fmaxf(a0, a1);
    float e0 = __expf(a0 - m), e1 = __expf(a1 - m);
    float s = e0 + e1;
    out[2 * b]     = e0 / s;
    out[2 * b + 1] = e1 / s;
  }
  for (int i = tid; i < 8192; i += 256) alpha[i] = 1.0f;
}

// ---------------------------------------------------------------------------
extern "C" void kernel_launch(void* const* d_in, const int* in_sizes, int n_in,
                              void* d_out, int out_size, void* d_ws, size_t ws_size,
                              hipStream_t stream) {
  const float* inp   = (const float*)d_in[0];   // [128,64,32,256]
  const float* convw = (const float*)d_in[1];   // [256]
  const float* convb = (const float*)d_in[2];   // [1]
  const float* embw  = (const float*)d_in[3];   // [256,256]
  const float* Wih   = (const float*)d_in[4];   // [2,2,384,256]
  const float* Whh   = (const float*)d_in[5];   // [2,2,384,128]
  const float* bih   = (const float*)d_in[6];   // [2,2,384]
  const float* bhh   = (const float*)d_in[7];   // [2,2,384]
  // d_in[8] att_w1: unused (softmax over size-1 axis == 1)
  const float* lw    = (const float*)d_in[9];   // [2,256]
  const float* lb    = (const float*)d_in[10];  // [2]

  char* ws = (char*)d_ws;
  u16*   convHi = (u16*)(ws);                         // 4 MiB; reused as states0
  u16*   convLo = (u16*)(ws + 4194304u);              // 4 MiB
  u16*   xbuf   = (u16*)(ws + 8388608u);              // 4 MiB
  u16*   embHi  = (u16*)(ws + 12582912u);             // 128 KiB
  u16*   embLo  = (u16*)(ws + 12713984u);             // 128 KiB
  u16*   wihB   = (u16*)(ws + 12845056u);             // 768 KiB
  float* xgbuf  = (float*)(ws + 13631488u);           // 24 MiB (reused L0/L1)
  u16*   states0 = convHi;

  float* outp    = (float*)d_out;       // [128,2]
  float* statesO = outp + 256;          // [128,64,256]
  float* ctxO    = outp + 2097408;      // [128,256]
  float* alphaO  = outp + 2130176;      // [128,1,64]

  // 0) fp32 weights -> bf16 (embed hi/lo; Wih single)
  k_cvt<<<1536, 256, 0, stream>>>(embw, Wih, embHi, embLo, wihB);

  // 1) conv -> hi/lo split of conv_all
  k_conv<<<8192, 256, 0, stream>>>(inp, convw, convb, convHi, convLo);

  // 2) embed: x = clip((Ahi+Alo)@(Whi+Wlo)^T), bf16 out.  M=8192,N=256,K=256
  dim3 gE(128, 4);
  k_gemm<true, true, false, true, true><<<gE, 256, 0, stream>>>(
      convHi, convLo, embHi, embLo, nullptr, xbuf, 8192, 256, 256);

  // 3) xg layer0 (both dirs fused: Wih[0] flat [768,256]) -> fp32
  dim3 gX(128, 12);
  k_gemm<false, false, true, false, false><<<gX, 256, 0, stream>>>(
      xbuf, nullptr, wihB, nullptr, bih, xgbuf, 8192, 768, 256);

  // 4) GRU layer 0 -> states0 bf16 (ws)
  k_gru<<<256, 384, 0, stream>>>(xgbuf, Whh, bhh, states0, nullptr, nullptr);

  // 5) xg layer1 from states0
  k_gemm<false, false, true, false, false><<<gX, 256, 0, stream>>>(
      states0, nullptr, wihB + 196608, nullptr, bih + 768, xgbuf, 8192, 768, 256);

  // 6) GRU layer 1 -> states fp32 (d_out) + context fp32 (d_out)
  k_gru<<<256, 384, 0, stream>>>(xgbuf, Whh + 98304, bhh + 768,
                                 nullptr, statesO, ctxO);

  // 7) out softmax + alpha ones (fp32)
  k_final<<<1, 256, 0, stream>>>(ctxO, lw, lb, outp, alphaO);
}

// Round 4
// 564.914 us; speedup vs baseline: 1.0840x; 1.0840x over previous
//
#include <hip/hip_runtime.h>

// Patient2Vec forward, MI355X/gfx950.
// Sizes: B=128,S=64,P=32,D=256,E=256,H=128,3H=384,L=2,A=1,O=2.
// Inputs fp32, outputs fp32. alpha == 1.0 exactly (softmax over size-1 axis);
// context = sum_t states.
// R4: GRU rewritten as per-chain MFMA recurrence (Whh in registers, hi/lo
// split); old scalar GRU spilled w[128] to scratch (~3.2 GiB traffic).

using u16 = unsigned short;
using u32 = unsigned int;

typedef __bf16 bf16x8 __attribute__((ext_vector_type(8)));
typedef float  f32x4  __attribute__((ext_vector_type(4)));

__device__ __forceinline__ float bf2f(u16 u) {
  union { u32 i; float f; } v; v.i = ((u32)u) << 16; return v.f;
}
__device__ __forceinline__ u16 f2bf(float f) {
  union { float f; u32 i; } v; v.f = f;
  u32 i = v.i;
  u32 r = (i + 0x7FFFu + ((i >> 16) & 1u)) >> 16;
  return (u16)r;
}
__device__ __forceinline__ float sigm(float x) { return 1.f / (1.f + __expf(-x)); }
__device__ __forceinline__ float tanh_f(float x) { return 1.f - 2.f / (1.f + __expf(2.f * x)); }

// split 8 fp32 -> hi/lo bf16x8
__device__ __forceinline__ void split8(const float* v, bf16x8& hi, bf16x8& lo) {
  union { bf16x8 v; u16 s[8]; } H, L;
#pragma unroll
  for (int j = 0; j < 8; j++) {
    u16 h = f2bf(v[j]);
    H.s[j] = h;
    L.s[j] = f2bf(v[j] - bf2f(h));
  }
  hi = H.v; lo = L.v;
}

// ---------------------------------------------------------------------------
// K0: weight conversion. embed_w fp32 -> hi/lo bf16; Wih fp32 -> bf16.
// ---------------------------------------------------------------------------
__global__ __launch_bounds__(256) void k_cvt(
    const float* __restrict__ embw, const float* __restrict__ Wih,
    u16* __restrict__ embHi, u16* __restrict__ embLo, u16* __restrict__ wihB) {
  const int i = blockIdx.x * 256 + threadIdx.x;
  if (i < 65536) {
    float v = embw[i];
    u16 h = f2bf(v);
    embHi[i] = h;
    embLo[i] = f2bf(v - bf2f(h));
  }
  wihB[i] = f2bf(Wih[i]);
}

// ---------------------------------------------------------------------------
// K1: conv — per (b,s): s_p = dot(inputs[b,s,p,:], conv_w)+cb;
//           conv_all[k] = sum_p s_p * inputs[b,s,p,k]
// fp32 in; emits hi/lo bf16 split of fp32 conv_all.
// ---------------------------------------------------------------------------
__global__ __launch_bounds__(256) void k_conv(
    const float* __restrict__ inp, const float* __restrict__ cw,
    const float* __restrict__ cb, u16* __restrict__ chi, u16* __restrict__ clo) {
  __shared__ float tile[32 * 256];  // 32 KiB
  __shared__ float cwf[256];
  __shared__ float s_p[32];
  const int bs  = blockIdx.x;
  const int tid = threadIdx.x;
  const float* src = inp + (size_t)bs * 8192;
#pragma unroll
  for (int i = 0; i < 8; i++) {
    int idx = i * 1024 + tid * 4;
    *(float4*)&tile[idx] = *(const float4*)&src[idx];
  }
  cwf[tid] = cw[tid];
  __syncthreads();
  const int wv = tid >> 6, ln = tid & 63;
  const float cbf = cb[0];
  for (int pp = 0; pp < 8; pp++) {
    int p = wv * 8 + pp;
    float part = 0.f;
#pragma unroll
    for (int q = 0; q < 4; q++) {
      int k = ln + q * 64;
      part += tile[p * 256 + k] * cwf[k];
    }
    for (int off = 32; off; off >>= 1) part += __shfl_xor(part, off, 64);
    if (ln == 0) s_p[p] = part + cbf;
  }
  __syncthreads();
  float acc = 0.f;
  const int k = tid;
#pragma unroll
  for (int p = 0; p < 32; p++) acc += s_p[p] * tile[p * 256 + k];
  u16 hi = f2bf(acc);
  float lo = acc - bf2f(hi);
  chi[(size_t)bs * 256 + k] = hi;
  clo[(size_t)bs * 256 + k] = f2bf(lo);
}

// ---------------------------------------------------------------------------
// K2: MFMA GEMM  C[m,n] = act( A[m,:]·W[n,:] (+Alo·W) (+A·Wlo) + bias[n] )
// 64x64 tile, 256 thr; verified round 3.
// ---------------------------------------------------------------------------
template <bool HAS_ALO, bool HAS_WLO, bool HAS_BIAS, bool CLIP, bool OUT_BF16>
__global__ __launch_bounds__(256) void k_gemm(
    const u16* __restrict__ A, const u16* __restrict__ Alo,
    const u16* __restrict__ W, const u16* __restrict__ Wlo,
    const float* __restrict__ bias,
    void* __restrict__ Cout, int M, int N, int K) {
  const int LDT = 56;
  __shared__ u16 As[64 * 56];
  __shared__ u16 La[64 * 56];
  __shared__ u16 Ws[64 * 56];
  __shared__ u16 Lw[64 * 56];
  const int tid = threadIdx.x;
  const int m0 = blockIdx.x * 64, n0 = blockIdx.y * 64;
  const int wv = tid >> 6, ln = tid & 63;
  const int lm = ln & 15, lk = (ln >> 4) * 8;
  const int srow = tid >> 2, sgrp = tid & 3;

  f32x4 acc[4];
#pragma unroll
  for (int nt = 0; nt < 4; nt++) acc[nt] = (f32x4){0.f, 0.f, 0.f, 0.f};

  for (int kc = 0; kc < K; kc += 32) {
    __syncthreads();
    *(uint4*)&As[srow * LDT + sgrp * 8] =
        *(const uint4*)&A[(size_t)(m0 + srow) * K + kc + sgrp * 8];
    *(uint4*)&Ws[srow * LDT + sgrp * 8] =
        *(const uint4*)&W[(size_t)(n0 + srow) * K + kc + sgrp * 8];
    if (HAS_ALO)
      *(uint4*)&La[srow * LDT + sgrp * 8] =
          *(const uint4*)&Alo[(size_t)(m0 + srow) * K + kc + sgrp * 8];
    if (HAS_WLO)
      *(uint4*)&Lw[srow * LDT + sgrp * 8] =
          *(const uint4*)&Wlo[(size_t)(n0 + srow) * K + kc + sgrp * 8];
    __syncthreads();

    bf16x8 af = *(const bf16x8*)&As[(wv * 16 + lm) * LDT + lk];
    bf16x8 bfr[4];
#pragma unroll
    for (int nt = 0; nt < 4; nt++)
      bfr[nt] = *(const bf16x8*)&Ws[(nt * 16 + lm) * LDT + lk];
#pragma unroll
    for (int nt = 0; nt < 4; nt++)
      acc[nt] = __builtin_amdgcn_mfma_f32_16x16x32_bf16(af, bfr[nt], acc[nt], 0, 0, 0);
    if (HAS_ALO) {
      bf16x8 lf = *(const bf16x8*)&La[(wv * 16 + lm) * LDT + lk];
#pragma unroll
      for (int nt = 0; nt < 4; nt++)
        acc[nt] = __builtin_amdgcn_mfma_f32_16x16x32_bf16(lf, bfr[nt], acc[nt], 0, 0, 0);
    }
    if (HAS_WLO) {
#pragma unroll
      for (int nt = 0; nt < 4; nt++) {
        bf16x8 wl = *(const bf16x8*)&Lw[(nt * 16 + lm) * LDT + lk];
        acc[nt] = __builtin_amdgcn_mfma_f32_16x16x32_bf16(af, wl, acc[nt], 0, 0, 0);
      }
    }
  }

  const int rbase = m0 + wv * 16 + (ln >> 4) * 4;
#pragma unroll
  for (int nt = 0; nt < 4; nt++) {
    const int col = n0 + nt * 16 + lm;
    const float bv = HAS_BIAS ? bias[col] : 0.f;
#pragma unroll
    for (int r = 0; r < 4; r++) {
      float v = acc[nt][r] + bv;
      if (CLIP) v = fminf(fmaxf(v, -1.f), 1.f);
      const int row = rbase + r;
      if (OUT_BF16)
        ((u16*)Cout)[(size_t)row * N + col] = f2bf(v);
      else
        ((float*)Cout)[(size_t)row * N + col] = v;
    }
  }
}

// ---------------------------------------------------------------------------
// K3: GRU layer via per-chain MFMA recurrence.
// One (b,dir) chain per block; 256 blocks; 512 threads = 8 waves.
// Wave w owns h-dims d in [w*16, w*16+16): gate tiles T=w (r), 8+w (z), 16+w (n).
// B-frags = Whh rows, hi/lo bf16 split, loop-invariant in REGISTERS
//   (3 tiles x 4 kt x 2 = 24 frags = 96 VGPR).
// A-frag: h replicated over M (all lanes read same 8-dim window) -> C rows all
//   equal gh; lane l<16 reg0 holds gh[T*16+l].
// h exchanged via 1KiB double-buffered LDS hi/lo u16; ONE barrier/step.
// gh = (Ahi+Alo)@Whi^T + Ahi@Wlo^T  (~fp32 precision).
// xg register-prefetched one step ahead.
// ---------------------------------------------------------------------------
__global__ __launch_bounds__(512, 2) void k_gru(
    const float* __restrict__ xg,   // [B*S,768], dir cols at dir*384
    const float* __restrict__ WhhL, // [2,384,128] layer slice fp32
    const float* __restrict__ bhhL, // [2,384] layer slice fp32
    u16* __restrict__ st_bf,        // [B,S,256] bf16 or null (layer0)
    float* __restrict__ st_f,       // [B,S,256] fp32 or null (layer1)
    float* __restrict__ ctx) {      // [B,256] fp32 or null (layer1)
  __shared__ __attribute__((aligned(16))) u16 hbHi[2][128];
  __shared__ __attribute__((aligned(16))) u16 hbLo[2][128];

  const int b   = blockIdx.x >> 1;
  const int dir = blockIdx.x & 1;
  const int tid = threadIdx.x;
  const int w   = tid >> 6, l = tid & 63;
  const int lm  = l & 15;            // col within tile / epilogue dim offset
  const int kw  = (l >> 4) * 8;      // k-window base within 32-chunk
  const int d   = w * 16 + lm;       // this lane's h-dim (epilogue if l<16)

  // --- loop-invariant W-frags in registers ---
  bf16x8 whi[3][4], wlo[3][4];
#pragma unroll
  for (int tt = 0; tt < 3; tt++) {
#pragma unroll
    for (int kt = 0; kt < 4; kt++) {
      const int row = (tt * 8 + w) * 16 + lm;          // gh row
      const float* p = WhhL + ((size_t)(dir * 384 + row)) * 128 + kt * 32 + kw;
      float v[8];
      *(float4*)&v[0] = *(const float4*)&p[0];
      *(float4*)&v[4] = *(const float4*)&p[4];
      split8(v, whi[tt][kt], wlo[tt][kt]);
    }
  }
  // biases for this lane's dim
  float bhr = 0.f, bhz = 0.f, bhn = 0.f;
  if (l < 16) {
    bhr = bhhL[dir * 384 + d];
    bhz = bhhL[dir * 384 + 128 + d];
    bhn = bhhL[dir * 384 + 256 + d];
  }
  // init h buffer 0
  if (tid < 128) { hbHi[0][tid] = 0; hbLo[0][tid] = 0; }

  const float* xbase = xg + (size_t)(b * 64) * 768 + dir * 384 + d;
  float xr = 0.f, xz = 0.f, xn = 0.f;
  if (l < 16) {
    const int t0 = dir ? 63 : 0;
    xr = xbase[t0 * 768];
    xz = xbase[t0 * 768 + 128];
    xn = xbase[t0 * 768 + 256];
  }
  float hold = 0.f, csum = 0.f;
  __syncthreads();

  int cur = 0;
  for (int ti = 0; ti < 64; ti++) {
    const int t = dir ? (63 - ti) : ti;
    // prefetch next step's xg
    float nxr = 0.f, nxz = 0.f, nxn = 0.f;
    if (l < 16 && ti < 63) {
      const int tn = dir ? (62 - ti) : (ti + 1);
      nxr = xbase[tn * 768];
      nxz = xbase[tn * 768 + 128];
      nxn = xbase[tn * 768 + 256];
    }
    // A-frags (h replicated over M)
    bf16x8 ahi[4], alo[4];
#pragma unroll
    for (int kt = 0; kt < 4; kt++) {
      ahi[kt] = *(const bf16x8*)&hbHi[cur][kt * 32 + kw];
      alo[kt] = *(const bf16x8*)&hbLo[cur][kt * 32 + kw];
    }
    f32x4 acc[3];
#pragma unroll
    for (int tt = 0; tt < 3; tt++) acc[tt] = (f32x4){0.f, 0.f, 0.f, 0.f};
#pragma unroll
    for (int kt = 0; kt < 4; kt++) {
#pragma unroll
      for (int tt = 0; tt < 3; tt++) {
        acc[tt] = __builtin_amdgcn_mfma_f32_16x16x32_bf16(ahi[kt], whi[tt][kt], acc[tt], 0, 0, 0);
        acc[tt] = __builtin_amdgcn_mfma_f32_16x16x32_bf16(alo[kt], whi[tt][kt], acc[tt], 0, 0, 0);
        acc[tt] = __builtin_amdgcn_mfma_f32_16x16x32_bf16(ahi[kt], wlo[tt][kt], acc[tt], 0, 0, 0);
      }
    }
    const int nxt = cur ^ 1;
    if (l < 16) {
      const float rg = sigm(xr + bhr + acc[0][0]);
      const float zg = sigm(xz + bhz + acc[1][0]);
      const float ng = tanh_f(xn + rg * (acc[2][0] + bhn));
      const float hn = (1.f - zg) * ng + zg * hold;
      hold = hn;
      csum += hn;
      const u16 hh = f2bf(hn);
      hbHi[nxt][d] = hh;
      hbLo[nxt][d] = f2bf(hn - bf2f(hh));
      const size_t oi = (size_t)(b * 64 + t) * 256 + dir * 128 + d;
      if (st_bf) st_bf[oi] = hh;
      if (st_f)  st_f[oi]  = hn;
    }
    __syncthreads();
    cur = nxt;
    xr = nxr; xz = nxz; xn = nxn;
  }
  if (ctx != nullptr && l < 16)
    ctx[(size_t)b * 256 + dir * 128 + d] = csum;
}

// ---------------------------------------------------------------------------
// K4: final — out = softmax(context @ lin_w^T + lin_b) over O=2; alpha = 1.0.
// ---------------------------------------------------------------------------
__global__ __launch_bounds__(256) void k_final(
    const float* __restrict__ ctx, const float* __restrict__ lw,
    const float* __restrict__ lb, float* __restrict__ out,
    float* __restrict__ alpha) {
  const int tid = threadIdx.x;
  if (tid < 128) {
    const int b = tid;
    float a0 = lb[0], a1 = lb[1];
    for (int k = 0; k < 256; k++) {
      float c = ctx[b * 256 + k];
      a0 += c * lw[k];
      a1 += c * lw[256 + k];
    }
    float m = fmaxf(a0, a1);
    float e0 = __expf(a0 - m), e1 = __expf(a1 - m);
    float s = e0 + e1;
    out[2 * b]     = e0 / s;
    out[2 * b + 1] = e1 / s;
  }
  for (int i = tid; i < 8192; i += 256) alpha[i] = 1.0f;
}

// ---------------------------------------------------------------------------
extern "C" void kernel_launch(void* const* d_in, const int* in_sizes, int n_in,
                              void* d_out, int out_size, void* d_ws, size_t ws_size,
                              hipStream_t stream) {
  const float* inp   = (const float*)d_in[0];   // [128,64,32,256]
  const float* convw = (const float*)d_in[1];   // [256]
  const float* convb = (const float*)d_in[2];   // [1]
  const float* embw  = (const float*)d_in[3];   // [256,256]
  const float* Wih   = (const float*)d_in[4];   // [2,2,384,256]
  const float* Whh   = (const float*)d_in[5];   // [2,2,384,128]
  const float* bih   = (const float*)d_in[6];   // [2,2,384]
  const float* bhh   = (const float*)d_in[7];   // [2,2,384]
  // d_in[8] att_w1: unused (softmax over size-1 axis == 1)
  const float* lw    = (const float*)d_in[9];   // [2,256]
  const float* lb    = (const float*)d_in[10];  // [2]

  char* ws = (char*)d_ws;
  u16*   convHi = (u16*)(ws);                         // 4 MiB; reused as states0
  u16*   convLo = (u16*)(ws + 4194304u);              // 4 MiB
  u16*   xbuf   = (u16*)(ws + 8388608u);              // 4 MiB
  u16*   embHi  = (u16*)(ws + 12582912u);             // 128 KiB
  u16*   embLo  = (u16*)(ws + 12713984u);             // 128 KiB
  u16*   wihB   = (u16*)(ws + 12845056u);             // 768 KiB
  float* xgbuf  = (float*)(ws + 13631488u);           // 24 MiB (reused L0/L1)
  u16*   states0 = convHi;

  float* outp    = (float*)d_out;       // [128,2]
  float* statesO = outp + 256;          // [128,64,256]
  float* ctxO    = outp + 2097408;      // [128,256]
  float* alphaO  = outp + 2130176;      // [128,1,64]

  // 0) fp32 weights -> bf16 (embed hi/lo; Wih single)
  k_cvt<<<1536, 256, 0, stream>>>(embw, Wih, embHi, embLo, wihB);

  // 1) conv -> hi/lo split of conv_all
  k_conv<<<8192, 256, 0, stream>>>(inp, convw, convb, convHi, convLo);

  // 2) embed: x = clip((Ahi+Alo)@(Whi+Wlo)^T), bf16 out.  M=8192,N=256,K=256
  dim3 gE(128, 4);
  k_gemm<true, true, false, true, true><<<gE, 256, 0, stream>>>(
      convHi, convLo, embHi, embLo, nullptr, xbuf, 8192, 256, 256);

  // 3) xg layer0 (both dirs fused: Wih[0] flat [768,256]) -> fp32
  dim3 gX(128, 12);
  k_gemm<false, false, true, false, false><<<gX, 256, 0, stream>>>(
      xbuf, nullptr, wihB, nullptr, bih, xgbuf, 8192, 768, 256);

  // 4) GRU layer 0 -> states0 bf16 (ws)
  k_gru<<<256, 512, 0, stream>>>(xgbuf, Whh, bhh, states0, nullptr, nullptr);

  // 5) xg layer1 from states0
  k_gemm<false, false, true, false, false><<<gX, 256, 0, stream>>>(
      states0, nullptr, wihB + 196608, nullptr, bih + 768, xgbuf, 8192, 768, 256);

  // 6) GRU layer 1 -> states fp32 (d_out) + context fp32 (d_out)
  k_gru<<<256, 512, 0, stream>>>(xgbuf, Whh + 98304, bhh + 768,
                                 nullptr, statesO, ctxO);

  // 7) out softmax + alpha ones (fp32)
  k_final<<<1, 256, 0, stream>>>(ctxO, lw, lb, outp, alphaO);
}